// Round 4
// baseline (105.997 us; speedup 1.0000x reference)
//
#include <hip/hip_runtime.h>
#include <math.h>

#define HH 256
#define WW 256
#define BB 2
#define NN 256
#define SPLIT 4
#define GPB (NN / SPLIT)          // gaussians per block slice (64)
#define ALPHA0 0.025f
#define BETA_ 2.0f
#define EPSF 1e-8f
#define PI_F 3.14159265358979323846f

// ws float layout:
//  [0..1]   alpha per batch
//  [2..3]   scale per batch
//  [4..5]   zmax encoded keys (unsigned, ordered-float encoding)
//  [16 .. 16 + B*N*16)            gaussian tables (16 floats each, float4-packed)
//  [PIX_OFF .. +B*SPLIT*HW*4)     per-pixel partial accum float4 (rgb, wsum)
#define GD_OFF 16
#define GD_STRIDE 16
#define PIX_OFF (GD_OFF + BB * NN * GD_STRIDE)   // 8208 floats (16B aligned)

__device__ __forceinline__ unsigned fkey(float f) {
    unsigned u = __float_as_uint(f);
    return u ^ ((unsigned)((int)u >> 31) | 0x80000000u);
}
__device__ __forceinline__ float funkey(unsigned k) {
    unsigned u = (k & 0x80000000u) ? (k ^ 0x80000000u) : ~k;
    return __uint_as_float(u);
}

// ---------------- Kernel 1: per-batch scale/alpha + per-gaussian tables ----
// table layout per gaussian (16 floats):
//  [0..3]  M00 M11 M22 2*M01   (M = rho diag(li) rho^T, symmetric)
//  [4..7]  2*M02 2*M12 v0 v1   (v = rho * (li*rho_mu))
//  [8..11] v2  msm  app0 app1
//  [12..15] app2 0 0 0
__global__ void __launch_bounds__(256) prep_kernel(const float* __restrict__ mu,
                                                   const float* __restrict__ rho,
                                                   const float* __restrict__ lambd,
                                                   const float* __restrict__ app,
                                                   float* __restrict__ ws) {
    const int b = blockIdx.x;
    const int t = threadIdx.x;
    __shared__ float red[256];
    __shared__ float s_scale;

    // min over lam (N*3 = 768 values)
    const float* lamB = lambd + b * NN * 3;
    float m = 3.4e38f;
    for (int i = t; i < NN * 3; i += 256) m = fminf(m, lamB[i]);
    red[t] = m;
    __syncthreads();
    for (int s = 128; s > 0; s >>= 1) {
        if (t < s) red[t] = fminf(red[t], red[t + s]);
        __syncthreads();
    }
    if (t == 0) {
        float minlam = red[0];
        float ls = ceilf(log10f(fmaxf(minlam, 1e-6f)));
        float scale = powf(10.0f, ls);
        ws[0 + b] = ALPHA0 * scale;
        ws[2 + b] = scale;
        ((unsigned*)ws)[4 + b] = fkey(-INFINITY);  // init zmax atomic slot
        s_scale = scale;
    }
    __syncthreads();
    const float scale = s_scale;

    // one gaussian per thread (N == blockDim)
    const int n = t;
    const float* rp = rho + (size_t)(b * NN + n) * 9;
    const float* mp = mu + (size_t)(b * NN + n) * 3;
    const float* lp = lambd + (size_t)(b * NN + n) * 3;
    const float* ap = app + (size_t)(b * NN + n) * 3;
    float r00 = rp[0], r01 = rp[1], r02 = rp[2];
    float r10 = rp[3], r11 = rp[4], r12 = rp[5];
    float r20 = rp[6], r21 = rp[7], r22 = rp[8];
    float m0 = mp[0], m1 = mp[1], m2 = mp[2];
    // rho_mu[k] = sum_c rho[c][k] * mu[c]
    float rm0 = r00 * m0 + r10 * m1 + r20 * m2;
    float rm1 = r01 * m0 + r11 * m1 + r21 * m2;
    float rm2 = r02 * m0 + r12 * m1 + r22 * m2;
    float li0 = scale / fmaxf(lp[0], EPSF);
    float li1 = scale / fmaxf(lp[1], EPSF);
    float li2 = scale / fmaxf(lp[2], EPSF);
    float g0 = li0 * rm0, g1 = li1 * rm1, g2 = li2 * rm2;
    float msm = g0 * rm0 + g1 * rm1 + g2 * rm2;

    float M00 = li0 * r00 * r00 + li1 * r01 * r01 + li2 * r02 * r02;
    float M11 = li0 * r10 * r10 + li1 * r11 * r11 + li2 * r12 * r12;
    float M22 = li0 * r20 * r20 + li1 * r21 * r21 + li2 * r22 * r22;
    float M01 = li0 * r00 * r10 + li1 * r01 * r11 + li2 * r02 * r12;
    float M02 = li0 * r00 * r20 + li1 * r01 * r21 + li2 * r02 * r22;
    float M12 = li0 * r10 * r20 + li1 * r11 * r21 + li2 * r12 * r22;
    float v0 = r00 * g0 + r01 * g1 + r02 * g2;
    float v1 = r10 * g0 + r11 * g1 + r12 * g2;
    float v2 = r20 * g0 + r21 * g1 + r22 * g2;

    float* gd = ws + GD_OFF + (size_t)(b * NN + n) * GD_STRIDE;
    gd[0] = M00;        gd[1] = M11;        gd[2] = M22;  gd[3] = 2.0f * M01;
    gd[4] = 2.0f * M02; gd[5] = 2.0f * M12; gd[6] = v0;   gd[7] = v1;
    gd[8] = v2;  gd[9] = msm; gd[10] = ap[0]; gd[11] = ap[1];
    gd[12] = ap[2]; gd[13] = 0.0f; gd[14] = 0.0f; gd[15] = 0.0f;
}

// ---------------- Kernel 2: heavy pass — per-pixel partial accum + z-max ---
// Gaussian table is read with a wave-uniform index through a const-restrict
// pointer (no stores through it) -> compiler emits scalar s_load_dwordx*,
// keeping the VALU free for math and eliminating all LDS staging.
__global__ void __launch_bounds__(256) accum_kernel(const float* __restrict__ K,
                                                    const float* __restrict__ hdr,
                                                    const float4* __restrict__ gdt,
                                                    float4* __restrict__ pacc,
                                                    unsigned* __restrict__ zslot) {
    const int by = blockIdx.y;           // b*SPLIT + slice
    const int b = by >> 2;
    const int h = by & (SPLIT - 1);
    const int t = threadIdx.x;
    __shared__ float wred[4];

    const float alpha = hdr[b];
    const float neg_inv_alpha = -1.0f / alpha;
    const float* Kb = K + b * 9;
    const float fx = Kb[0], cx = Kb[2], fy = Kb[4], cy = Kb[5];

    const int pix = blockIdx.x * 256 + t;
    const int px = pix & (WW - 1);
    const int py = pix >> 8;
    float rx = ((float)px - cx) / fx;
    float ry = ((float)py - cy) / fy;
    float inn = __builtin_amdgcn_rsqf(rx * rx + ry * ry + 1.0f);
    const float r0 = rx * inn, r1 = ry * inn, r2 = inn;
    const float q0 = r0 * r0, q1 = r1 * r1, q2 = r2 * r2;
    const float q3 = r0 * r1, q4 = r0 * r2, q5 = r1 * r2;  // 2x folded into table

    float wsum = 0.0f, c0 = 0.0f, c1 = 0.0f, c2 = 0.0f;
    float zmax = -INFINITY;

    const float4* g = gdt + (size_t)(b * NN + h * GPB) * 4;
#pragma unroll 4
    for (int n = 0; n < GPB; ++n) {
        float4 A = g[n * 4 + 0];   // M00 M11 M22 2M01
        float4 Bv = g[n * 4 + 1];  // 2M02 2M12 v0 v1
        float4 C = g[n * 4 + 2];   // v2  msm app0 app1
        float4 D = g[n * 4 + 3];   // app2 - - -

        float rsr = fmaf(A.x, q0, fmaf(A.y, q1, fmaf(A.z, q2,
                    fmaf(A.w, q3, fmaf(Bv.x, q4, Bv.y * q5)))));
        float rsm = fmaf(Bv.z, r0, fmaf(Bv.w, r1, C.x * r2));
        float rsrc = fmaxf(rsr, EPSF);
        float rsq = __builtin_amdgcn_rsqf(rsrc);   // 1/sqrt(rsr)
        float rcp = rsq * rsq;                     // 1/rsr
        float z = rsm * rcp;
        zmax = fmaxf(zmax, z);
        float d = fmaf(-rsm, z, C.y);              // msm - rsm^2/rsr
        float ee = __expf(fminf(d * neg_inv_alpha, 8.0f));
        float z2 = z * z;
        float z4 = z2 * z2;
        float den = __builtin_amdgcn_rcpf(1.0f + z4);
        float w = ee * rsq * den;                  // 'a' factored out (finish)
        wsum += w;
        c0 = fmaf(w, C.z, c0);
        c1 = fmaf(w, C.w, c1);
        c2 = fmaf(w, D.x, c2);
    }

    pacc[(size_t)by * (HH * WW) + pix] = make_float4(c0, c1, c2, wsum);

    // block-reduce zmax -> per-batch atomic
    for (int off = 32; off >= 1; off >>= 1)
        zmax = fmaxf(zmax, __shfl_down(zmax, off, 64));
    if ((t & 63) == 0) wred[t >> 6] = zmax;
    __syncthreads();
    if (t == 0) {
        float zm = fmaxf(fmaxf(wred[0], wred[1]), fmaxf(wred[2], wred[3]));
        atomicMax(zslot + 4 + b, fkey(zm));
    }
}

// ---------------- Kernel 3: epilogue — background + normalize + write -----
__global__ void __launch_bounds__(256) finish_kernel(const float* __restrict__ bg_app,
                                                     float* __restrict__ out,
                                                     const float* __restrict__ ws) {
    const int b = blockIdx.y;
    const int tid = blockIdx.x * 256 + threadIdx.x;
    const int p = tid * 4;                    // 4 consecutive pixels per thread

    const float alpha = ws[b];
    const float a = 0.5f * sqrtf(PI_F * alpha);
    const float zmax = funkey(((const unsigned*)ws)[4 + b]);
    const float zbg = BETA_ * zmax;
    const float zb2 = zbg * zbg;
    const float zb4 = zb2 * zb2;
    const float wbg = a / (1.0f + zb4);       // bg_int = a (erfc clipped to 1)
    const float b0 = bg_app[b * 3 + 0], b1 = bg_app[b * 3 + 1], b2 = bg_app[b * 3 + 2];

    const int hw = HH * WW;
    const float4* acc = (const float4*)(ws + PIX_OFF) + (size_t)(b * SPLIT) * hw;

    float4 o0, o1, o2;
    float* po0 = &o0.x; float* po1 = &o1.x; float* po2 = &o2.x;
    for (int j = 0; j < 4; ++j) {
        float4 s0 = acc[p + j];
        float4 s1 = acc[p + j + hw];
        float4 s2 = acc[p + j + 2 * hw];
        float4 s3 = acc[p + j + 3 * hw];
        float sx = (s0.x + s1.x) + (s2.x + s3.x);
        float sy = (s0.y + s1.y) + (s2.y + s3.y);
        float sz = (s0.z + s1.z) + (s2.z + s3.z);
        float sw = (s0.w + s1.w) + (s2.w + s3.w);
        float tot = fmaf(a, sw, wbg);
        float inv = 1.0f / fmaxf(tot, EPSF);
        po0[j] = fmaf(a, sx, wbg * b0) * inv;
        po1[j] = fmaf(a, sy, wbg * b1) * inv;
        po2[j] = fmaf(a, sz, wbg * b2) * inv;
    }
    *(float4*)(out + (size_t)(b * 3) * hw + p) = o0;
    *(float4*)(out + (size_t)(b * 3 + 1) * hw + p) = o1;
    *(float4*)(out + (size_t)(b * 3 + 2) * hw + p) = o2;
}

extern "C" void kernel_launch(void* const* d_in, const int* in_sizes, int n_in,
                              void* d_out, int out_size, void* d_ws, size_t ws_size,
                              hipStream_t stream) {
    const float* mu = (const float*)d_in[0];
    const float* rho = (const float*)d_in[1];
    const float* lambd = (const float*)d_in[2];
    const float* app = (const float*)d_in[3];
    const float* bg = (const float*)d_in[4];
    const float* K = (const float*)d_in[5];
    float* ws = (float*)d_ws;
    float* out = (float*)d_out;

    hipLaunchKernelGGL(prep_kernel, dim3(BB), dim3(256), 0, stream, mu, rho, lambd, app, ws);
    dim3 grid(HH * WW / 256, BB * SPLIT);
    hipLaunchKernelGGL(accum_kernel, grid, dim3(256), 0, stream,
                       K, ws, (const float4*)(ws + GD_OFF),
                       (float4*)(ws + PIX_OFF), (unsigned*)ws);
    dim3 fgrid(HH * WW / (256 * 4), BB);
    hipLaunchKernelGGL(finish_kernel, fgrid, dim3(256), 0, stream, bg, out, ws);
}

// Round 5
// 98.813 us; speedup vs baseline: 1.0727x; 1.0727x over previous
//
#include <hip/hip_runtime.h>
#include <math.h>

#define HH 256
#define WW 256
#define BB 2
#define NN 256
#define SPLIT 4
#define GPB (NN / SPLIT)          // gaussians per block slice (64)
#define BX 128                    // pixel-blocks per slice (2 px per thread)
#define ALPHA0 0.025f
#define BETA_ 2.0f
#define EPSF 1e-8f
#define PI_F 3.14159265358979323846f

// ws float layout:
//  [0 .. BB*SPLIT*BX)                  per-block zmax partials (1024 floats)
//  [PIX_OFF .. +BB*SPLIT*HW*4)         per-pixel partial accum float4 (rgb, wsum)
#define ZP_OFF 0
#define PIX_OFF (BB * SPLIT * BX)       // 1024 floats -> 4096 B, 16B aligned

// ---------------- Kernel 1: fused prep + heavy accumulation ---------------
// Each block: (a) λ-min reduce -> scale/alpha (redundant per block, trivial),
// (b) builds its 64-gaussian table slice in LDS, (c) 2 pixels/thread over the
// slice, (d) block zmax -> per-block slot (no atomics, poison-safe).
__global__ void __launch_bounds__(256) accum_kernel(const float* __restrict__ mu,
                                                    const float* __restrict__ rho,
                                                    const float* __restrict__ lambd,
                                                    const float* __restrict__ app,
                                                    const float* __restrict__ K,
                                                    float4* __restrict__ pacc,
                                                    float* __restrict__ zpart) {
    const int by = blockIdx.y;           // b*SPLIT + slice
    const int b = by >> 2;
    const int h = by & (SPLIT - 1);
    const int t = threadIdx.x;
    __shared__ float4 gd[GPB * 4];       // 64 gaussians * 16 floats = 4 KB
    __shared__ float red[256];
    __shared__ float s_scale;

    // --- per-batch lambda min -> scale ---
    const float* lamB = lambd + b * NN * 3;
    float m = 3.4e38f;
    for (int i = t; i < NN * 3; i += 256) m = fminf(m, lamB[i]);
    red[t] = m;
    __syncthreads();
    for (int s = 128; s > 0; s >>= 1) {
        if (t < s) red[t] = fminf(red[t], red[t + s]);
        __syncthreads();
    }
    if (t == 0) {
        float ls = ceilf(log10f(fmaxf(red[0], 1e-6f)));
        s_scale = powf(10.0f, ls);
    }
    __syncthreads();
    const float scale = s_scale;
    const float alpha = ALPHA0 * scale;
    const float neg_inv_alpha = -1.0f / alpha;

    // --- build gaussian table slice in LDS ---
    if (t < GPB) {
        const int gi = b * NN + h * GPB + t;
        const float* rp = rho + (size_t)gi * 9;
        const float* mp = mu + (size_t)gi * 3;
        const float* lp = lambd + (size_t)gi * 3;
        const float* ap = app + (size_t)gi * 3;
        float r00 = rp[0], r01 = rp[1], r02 = rp[2];
        float r10 = rp[3], r11 = rp[4], r12 = rp[5];
        float r20 = rp[6], r21 = rp[7], r22 = rp[8];
        float m0 = mp[0], m1 = mp[1], m2 = mp[2];
        float rm0 = r00 * m0 + r10 * m1 + r20 * m2;
        float rm1 = r01 * m0 + r11 * m1 + r21 * m2;
        float rm2 = r02 * m0 + r12 * m1 + r22 * m2;
        float li0 = scale / fmaxf(lp[0], EPSF);
        float li1 = scale / fmaxf(lp[1], EPSF);
        float li2 = scale / fmaxf(lp[2], EPSF);
        float g0 = li0 * rm0, g1 = li1 * rm1, g2 = li2 * rm2;
        float msm = g0 * rm0 + g1 * rm1 + g2 * rm2;
        float M00 = li0 * r00 * r00 + li1 * r01 * r01 + li2 * r02 * r02;
        float M11 = li0 * r10 * r10 + li1 * r11 * r11 + li2 * r12 * r12;
        float M22 = li0 * r20 * r20 + li1 * r21 * r21 + li2 * r22 * r22;
        float M01 = li0 * r00 * r10 + li1 * r01 * r11 + li2 * r02 * r12;
        float M02 = li0 * r00 * r20 + li1 * r01 * r21 + li2 * r02 * r22;
        float M12 = li0 * r10 * r20 + li1 * r11 * r21 + li2 * r12 * r22;
        float v0 = r00 * g0 + r01 * g1 + r02 * g2;
        float v1 = r10 * g0 + r11 * g1 + r12 * g2;
        float v2 = r20 * g0 + r21 * g1 + r22 * g2;
        gd[t * 4 + 0] = make_float4(M00, M11, M22, 2.0f * M01);
        gd[t * 4 + 1] = make_float4(2.0f * M02, 2.0f * M12, v0, v1);
        gd[t * 4 + 2] = make_float4(v2, msm, ap[0], ap[1]);
        gd[t * 4 + 3] = make_float4(ap[2], 0.0f, 0.0f, 0.0f);
    }
    __syncthreads();

    // --- two pixels per thread ---
    const float* Kb = K + b * 9;
    const float fx = Kb[0], cx = Kb[2], fy = Kb[4], cy = Kb[5];
    const int pix0 = blockIdx.x * 512 + t;
    const int pix1 = pix0 + 256;

    float rxa = ((float)(pix0 & (WW - 1)) - cx) / fx;
    float rya = ((float)(pix0 >> 8) - cy) / fy;
    float inna = __builtin_amdgcn_rsqf(rxa * rxa + rya * rya + 1.0f);
    const float r0a = rxa * inna, r1a = rya * inna, r2a = inna;
    const float q0a = r0a * r0a, q1a = r1a * r1a, q2a = r2a * r2a;
    const float q3a = r0a * r1a, q4a = r0a * r2a, q5a = r1a * r2a;

    float rxb = ((float)(pix1 & (WW - 1)) - cx) / fx;
    float ryb = ((float)(pix1 >> 8) - cy) / fy;
    float innb = __builtin_amdgcn_rsqf(rxb * rxb + ryb * ryb + 1.0f);
    const float r0b = rxb * innb, r1b = ryb * innb, r2b = innb;
    const float q0b = r0b * r0b, q1b = r1b * r1b, q2b = r2b * r2b;
    const float q3b = r0b * r1b, q4b = r0b * r2b, q5b = r1b * r2b;

    float wsa = 0.0f, c0a = 0.0f, c1a = 0.0f, c2a = 0.0f, zma = -INFINITY;
    float wsb = 0.0f, c0b = 0.0f, c1b = 0.0f, c2b = 0.0f, zmb = -INFINITY;

#pragma unroll 2
    for (int n = 0; n < GPB; ++n) {
        float4 A = gd[n * 4 + 0];   // M00 M11 M22 2M01
        float4 Bv = gd[n * 4 + 1];  // 2M02 2M12 v0 v1
        float4 C = gd[n * 4 + 2];   // v2  msm app0 app1
        float4 D = gd[n * 4 + 3];   // app2 - - -

        float rsra = fmaf(A.x, q0a, fmaf(A.y, q1a, fmaf(A.z, q2a,
                     fmaf(A.w, q3a, fmaf(Bv.x, q4a, Bv.y * q5a)))));
        float rsrb = fmaf(A.x, q0b, fmaf(A.y, q1b, fmaf(A.z, q2b,
                     fmaf(A.w, q3b, fmaf(Bv.x, q4b, Bv.y * q5b)))));
        float rsma = fmaf(Bv.z, r0a, fmaf(Bv.w, r1a, C.x * r2a));
        float rsmb = fmaf(Bv.z, r0b, fmaf(Bv.w, r1b, C.x * r2b));

        float rsqa = __builtin_amdgcn_rsqf(fmaxf(rsra, EPSF));
        float rsqb = __builtin_amdgcn_rsqf(fmaxf(rsrb, EPSF));
        float za = rsma * (rsqa * rsqa);
        float zb = rsmb * (rsqb * rsqb);
        zma = fmaxf(zma, za);
        zmb = fmaxf(zmb, zb);
        float da = fmaf(-rsma, za, C.y);
        float db = fmaf(-rsmb, zb, C.y);
        float eea = __expf(fminf(da * neg_inv_alpha, 8.0f));
        float eeb = __expf(fminf(db * neg_inv_alpha, 8.0f));
        float z2a = za * za, z4a = z2a * z2a;
        float z2b = zb * zb, z4b = z2b * z2b;
        float dena = __builtin_amdgcn_rcpf(1.0f + z4a);
        float denb = __builtin_amdgcn_rcpf(1.0f + z4b);
        float wa = eea * rsqa * dena;              // 'a' factored out (finish)
        float wb = eeb * rsqb * denb;
        wsa += wa;
        c0a = fmaf(wa, C.z, c0a); c1a = fmaf(wa, C.w, c1a); c2a = fmaf(wa, D.x, c2a);
        wsb += wb;
        c0b = fmaf(wb, C.z, c0b); c1b = fmaf(wb, C.w, c1b); c2b = fmaf(wb, D.x, c2b);
    }

    float4* dst = pacc + (size_t)by * (HH * WW);
    dst[pix0] = make_float4(c0a, c1a, c2a, wsa);
    dst[pix1] = make_float4(c0b, c1b, c2b, wsb);

    // --- block zmax -> per-block slot (no atomic, no init dependency) ---
    float zm = fmaxf(zma, zmb);
    for (int off = 32; off >= 1; off >>= 1)
        zm = fmaxf(zm, __shfl_down(zm, off, 64));
    __syncthreads();                 // gd/red no longer needed
    if ((t & 63) == 0) red[t >> 6] = zm;
    __syncthreads();
    if (t == 0)
        zpart[by * BX + blockIdx.x] =
            fmaxf(fmaxf(red[0], red[1]), fmaxf(red[2], red[3]));
}

// ---------------- Kernel 2: epilogue — zmax reduce + bg + normalize -------
__global__ void __launch_bounds__(256) finish_kernel(const float* __restrict__ lambd,
                                                     const float* __restrict__ bg_app,
                                                     float* __restrict__ out,
                                                     const float* __restrict__ zpart,
                                                     const float4* __restrict__ pacc) {
    const int b = blockIdx.y;
    const int t = threadIdx.x;
    __shared__ float red[256];

    // λ-min -> scale/alpha (redundant recompute, trivial)
    const float* lamB = lambd + b * NN * 3;
    float m = 3.4e38f;
    for (int i = t; i < NN * 3; i += 256) m = fminf(m, lamB[i]);
    red[t] = m;
    __syncthreads();
    for (int s = 128; s > 0; s >>= 1) {
        if (t < s) red[t] = fminf(red[t], red[t + s]);
        __syncthreads();
    }
    const float minlam = red[0];
    __syncthreads();

    // zmax over this batch's 512 block slots
    const float* zp = zpart + b * SPLIT * BX;
    float zm = fmaxf(zp[t], zp[t + 256]);
    red[t] = zm;
    __syncthreads();
    for (int s = 128; s > 0; s >>= 1) {
        if (t < s) red[t] = fmaxf(red[t], red[t + s]);
        __syncthreads();
    }
    const float zmax = red[0];

    const float scale = powf(10.0f, ceilf(log10f(fmaxf(minlam, 1e-6f))));
    const float alpha = ALPHA0 * scale;
    const float a = 0.5f * sqrtf(PI_F * alpha);
    const float zbg = BETA_ * zmax;
    const float zb2 = zbg * zbg;
    const float zb4 = zb2 * zb2;
    const float wbg = a / (1.0f + zb4);       // bg_int = a (erfc clipped to 1)
    const float b0 = bg_app[b * 3 + 0], b1 = bg_app[b * 3 + 1], b2 = bg_app[b * 3 + 2];

    const int hw = HH * WW;
    const int tid = blockIdx.x * 256 + t;
    const int p = tid * 4;                    // 4 consecutive pixels per thread
    const float4* acc = pacc + (size_t)(b * SPLIT) * hw;

    float4 o0, o1, o2;
    float* po0 = &o0.x; float* po1 = &o1.x; float* po2 = &o2.x;
    for (int j = 0; j < 4; ++j) {
        float4 s0 = acc[p + j];
        float4 s1 = acc[p + j + hw];
        float4 s2 = acc[p + j + 2 * hw];
        float4 s3 = acc[p + j + 3 * hw];
        float sx = (s0.x + s1.x) + (s2.x + s3.x);
        float sy = (s0.y + s1.y) + (s2.y + s3.y);
        float sz = (s0.z + s1.z) + (s2.z + s3.z);
        float sw = (s0.w + s1.w) + (s2.w + s3.w);
        float tot = fmaf(a, sw, wbg);
        float inv = 1.0f / fmaxf(tot, EPSF);
        po0[j] = fmaf(a, sx, wbg * b0) * inv;
        po1[j] = fmaf(a, sy, wbg * b1) * inv;
        po2[j] = fmaf(a, sz, wbg * b2) * inv;
    }
    *(float4*)(out + (size_t)(b * 3) * hw + p) = o0;
    *(float4*)(out + (size_t)(b * 3 + 1) * hw + p) = o1;
    *(float4*)(out + (size_t)(b * 3 + 2) * hw + p) = o2;
}

extern "C" void kernel_launch(void* const* d_in, const int* in_sizes, int n_in,
                              void* d_out, int out_size, void* d_ws, size_t ws_size,
                              hipStream_t stream) {
    const float* mu = (const float*)d_in[0];
    const float* rho = (const float*)d_in[1];
    const float* lambd = (const float*)d_in[2];
    const float* app = (const float*)d_in[3];
    const float* bg = (const float*)d_in[4];
    const float* K = (const float*)d_in[5];
    float* ws = (float*)d_ws;
    float* out = (float*)d_out;

    dim3 agrid(BX, BB * SPLIT);
    hipLaunchKernelGGL(accum_kernel, agrid, dim3(256), 0, stream,
                       mu, rho, lambd, app, K,
                       (float4*)(ws + PIX_OFF), ws + ZP_OFF);
    dim3 fgrid(HH * WW / (256 * 4), BB);
    hipLaunchKernelGGL(finish_kernel, fgrid, dim3(256), 0, stream,
                       lambd, bg, out, ws + ZP_OFF, (const float4*)(ws + PIX_OFF));
}